// Round 14
// baseline (70.329 us; speedup 1.0000x reference)
//
#include <hip/hip_runtime.h>
#include <stdint.h>
#include <math.h>

#define NEGV (-1e30f)

constexpr int L1_ = 512;
constexpr int H_  = 128;
constexpr int NK_ = 2048;   // 32 turns * 64 tokens

typedef __attribute__((ext_vector_type(8))) _Float16 f16x8;
typedef __attribute__((ext_vector_type(2))) __fp16   h16x2;
typedef __attribute__((ext_vector_type(4))) float    f32x4;

static __device__ __forceinline__ uint16_t f2h(float x) {
    union { _Float16 h; uint16_t u; } cv; cv.h = (_Float16)x; return cv.u;
}

// Fragment-major layouts (16B chunk per lane, lane = (g<<4)|n16):
//  Y2[kt(32)][kkT(4)][ks(4)][lane]  chunk = yp[kt*64+kkT*16+n16][ks*32+g*8 .. +8]
//  V2[kt(32)][cT(8)][ks(2)][lane]   chunk = dlg[kt*64+ks*32+g*8+j][cT*16+n16]
//  W2[cT(8)][ks(4)][lane]           chunk = W [cT*16+n16][ks*32+g*8 .. +8]

// ---------------------------------------------------------------------------
// Preprocessing, 256 threads/block (unchanged):
//  [0,128): yproj->Y2   [128,160): dlg->V2   160: badd   161: W->W2
// ---------------------------------------------------------------------------
__global__ __launch_bounds__(256) void preproc_kernel(
        const float* __restrict__ xq,
        const float* __restrict__ xa,
        const float* __restrict__ W,
        const float* __restrict__ bias,
        const uint8_t* __restrict__ qm,
        const uint8_t* __restrict__ am,
        uint8_t* __restrict__ Y2,
        uint8_t* __restrict__ V2,
        uint8_t* __restrict__ W2,
        float* __restrict__ badd) {
    int b = blockIdx.x;
    int tid = threadIdx.x;
    __shared__ __align__(16) float sbuf[64 * 128];   // 32 KB

    if (b < 128) {
        int k0 = b * 16;
        f32x4* xr4 = (f32x4*)sbuf;
#pragma unroll
        for (int i = 0; i < 2; ++i) {
            int idx = tid + i * 256;
            int row = idx >> 5, d4 = idx & 31;
            int k = k0 + row;
            int b2 = k >> 6, r = k & 63;
            const float* src = (r < 32) ? (xq + (size_t)(b2 * 32 + r) * H_)
                                        : (xa + (size_t)(b2 * 32 + (r - 32)) * H_);
            xr4[idx] = *(const f32x4*)(src + d4 * 4);
        }
        __syncthreads();
        int c = tid & 127, rh = tid >> 7;
        float acc[8];
#pragma unroll
        for (int i = 0; i < 8; ++i) acc[i] = 0.0f;
        const f32x4* w4 = (const f32x4*)(W + (size_t)c * H_);
        for (int d4 = 0; d4 < 32; ++d4) {
            f32x4 wv = w4[d4];
#pragma unroll
            for (int i = 0; i < 8; ++i) {
                f32x4 x = xr4[(rh * 8 + i) * 32 + d4];
                acc[i] += wv[0]*x[0] + wv[1]*x[1] + wv[2]*x[2] + wv[3]*x[3];
            }
        }
        float bc = bias[c];
        float* res = sbuf + 2048;
#pragma unroll
        for (int i = 0; i < 8; ++i)
            res[(rh * 8 + i) * H_ + c] = fmaxf(acc[i] + bc, 0.0f);
        __syncthreads();
        int ks = tid >> 6, l = tid & 63, n16 = l & 15, g = l >> 4;
        uint16_t hbuf[8];
#pragma unroll
        for (int j = 0; j < 8; ++j)
            hbuf[j] = f2h(res[n16 * H_ + ks * 32 + g * 8 + j]);
        uint8_t* dst = Y2 + (((size_t)b * 4 + ks) << 10) + l * 16;
        *(uint64_t*)dst       = ((const uint64_t*)hbuf)[0];
        *(uint64_t*)(dst + 8) = ((const uint64_t*)hbuf)[1];
    } else if (b < 160) {
        int kt = b - 128;
        f32x4* ld4 = (f32x4*)sbuf;
#pragma unroll
        for (int i = 0; i < 8; ++i) {
            int idx = tid + i * 256;
            int row = idx >> 5, d4 = idx & 31;
            const float* src = (row < 32) ? (xq + (size_t)(kt * 32 + row) * H_)
                                          : (xa + (size_t)(kt * 32 + row - 32) * H_);
            ld4[idx] = *(const f32x4*)(src + d4 * 4);
        }
        __syncthreads();
#pragma unroll
        for (int i = 0; i < 4; ++i) {
            int id = tid + i * 256;
            int cT = id >> 7, ks = (id >> 6) & 1, l = id & 63;
            int n16 = l & 15, g = l >> 4;
            uint16_t hbuf[8];
#pragma unroll
            for (int j = 0; j < 8; ++j)
                hbuf[j] = f2h(sbuf[(ks * 32 + g * 8 + j) * H_ + cT * 16 + n16]);
            uint8_t* dst = V2 + (((size_t)kt * 16 + cT * 2 + ks) << 10) + l * 16;
            *(uint64_t*)dst       = ((const uint64_t*)hbuf)[0];
            *(uint64_t*)(dst + 8) = ((const uint64_t*)hbuf)[1];
        }
    } else if (b == 160) {
        int* flags = (int*)sbuf;
        if (tid == 0) { flags[0] = 0; flags[1] = 0; }
        __syncthreads();
        uint32_t v = ((const uint32_t*)qm)[tid] | ((const uint32_t*)am)[tid];
        if (v & 0xFFu)        atomicOr(&flags[0], 1);
        if (v & 0xFFFFFF00u)  atomicOr(&flags[1], 1);
        __syncthreads();
        int f0 = flags[0], f1 = flags[1];
        int mode = (f0 && !f1) ? 0 : ((!f0 && f1) ? 1 : 2);
        for (int k = tid; k < NK_; k += 256) {
            int b2 = k >> 6, r = k & 63;
            int idx = b2 * 32 + (r < 32 ? r : r - 32);
            const uint8_t* src = (r < 32) ? qm : am;
            int p;
            if (mode == 0)      p = (((const int*)src)[idx] != 0);
            else if (mode == 1) p = (((const float*)src)[idx] != 0.0f);
            else                p = (src[idx] != 0);
            badd[k] = p ? NEGV : 0.0f;
        }
    } else {
        for (int h = 0; h < 2; ++h) {
            f32x4* s4 = (f32x4*)sbuf;
#pragma unroll
            for (int i = 0; i < 8; ++i) {
                int idx = tid + i * 256;
                s4[idx] = *(const f32x4*)(W + (size_t)h * 64 * H_ + idx * 4);
            }
            __syncthreads();
#pragma unroll
            for (int i = 0; i < 4; ++i) {
                int id = tid + i * 256;
                int ct = id >> 8, ks = (id >> 6) & 3, l = id & 63;
                int n16 = l & 15, g = l >> 4;
                uint16_t hb[8];
#pragma unroll
                for (int j = 0; j < 8; ++j)
                    hb[j] = f2h(sbuf[(ct * 16 + n16) * H_ + ks * 32 + g * 8 + j]);
                uint8_t* dst = W2 + (((size_t)((h * 4 + ct) * 4 + ks)) << 10) + l * 16;
                *(uint64_t*)dst       = ((const uint64_t*)hb)[0];
                *(uint64_t*)(dst + 8) = ((const uint64_t*)hb)[1];
            }
            __syncthreads();
        }
    }
}

// ---------------------------------------------------------------------------
// Flash attention, balanced split-K, low register pressure.
// Job = (t, l32, khalf). 256 thr / 4 waves = 2 rg (16 rows) x 2 kh (k-stride 2).
// Per-wave: acc[8] (32 VGPR), xf[4] (16) -> live set ~100, fits 128 cap.
// Writes unnormalized partial (O, M, L); combine kernel folds h-halves.
// ---------------------------------------------------------------------------
__global__ __launch_bounds__(256, 2) void attn_kernel(
        const float*   __restrict__ xd,
        const uint8_t* __restrict__ W2,
        const float*   __restrict__ bias,
        const uint8_t* __restrict__ Y2,
        const uint8_t* __restrict__ V2,
        const float*   __restrict__ badd,
        const float*   __restrict__ rw,
        float* __restrict__ Opart,
        float* __restrict__ mstat,
        float* __restrict__ lstat) {
    int bid = blockIdx.x;
    int r8 = bid & 255, qq = bid >> 8;
    int tt = r8 >> 4, l = r8 & 15;
    int t = (qq & 1) ? tt : (31 - tt);
    int h = qq >> 1;
    if (t == 0) return;            // combine writes zeros for t=0
    int l0 = l << 5;
    int lo = h ? ((t + 1) >> 1) : 0;
    int hi = h ? t : ((t + 1) >> 1);
    int tid = threadIdx.x;

    __shared__ __align__(16) char LDSA[24576];  // P[0,8K) | xpbuf[8K,16K) | xbuf[16K,24K); epilogue Ob=[0,16K)
    __shared__ float stats_m[4][16];
    __shared__ float stats_l[4][16];

    int w = tid >> 6, lane = tid & 63, n16 = lane & 15, g = lane >> 4;
    int rg = w >> 1, kh = w & 1;
    int swzP = (n16 & 7) << 4;
    char* xpbuf = LDSA + 8192;
    char* xbuf  = LDSA + 16384;
    char* Pw    = LDSA + w * 2048;     // 16 rows x 128 B per wave

    // ================= x-projection prologue (MFMA, all 32 rows) ============
    {
        const float* xsrc = xd + (size_t)(t * L1_ + l0) * H_;
#pragma unroll
        for (int i = 0; i < 4; ++i) {
            int idx = tid + i * 256;          // 1024 f32x4 = 32 rows
            int row = idx >> 5, c4 = idx & 31;
            f32x4 v = *(const f32x4*)(xsrc + idx * 4);
            uint16_t hb[4] = { f2h(v[0]), f2h(v[1]), f2h(v[2]), f2h(v[3]) };
            *(uint64_t*)(xbuf + row * 256 + ((c4 * 8) ^ ((row & 7) << 4))) = *(const uint64_t*)hb;
        }
    }
    __syncthreads();
    {
        f16x8 af[2][4];
#pragma unroll
        for (int rT = 0; rT < 2; ++rT) {
            int row = rT * 16 + n16, swz = (row & 7) << 4;
#pragma unroll
            for (int ks = 0; ks < 4; ++ks)
                af[rT][ks] = *(const f16x8*)(xbuf + row * 256 + ((ks * 64 + g * 16) ^ swz));
        }
        int cTa = 2 * w, cTb = 2 * w + 1;
        f32x4 z4 = {0.f, 0.f, 0.f, 0.f};
        f32x4 d00 = z4, d01 = z4, d10 = z4, d11 = z4;
#pragma unroll
        for (int ks = 0; ks < 4; ++ks) {
            f16x8 wfa = *(const f16x8*)(W2 + (((size_t)cTa * 4 + ks) << 10) + lane * 16);
            f16x8 wfb = *(const f16x8*)(W2 + (((size_t)cTb * 4 + ks) << 10) + lane * 16);
            d00 = __builtin_amdgcn_mfma_f32_16x16x32_f16(af[0][ks], wfa, d00, 0, 0, 0);
            d10 = __builtin_amdgcn_mfma_f32_16x16x32_f16(af[1][ks], wfa, d10, 0, 0, 0);
            d01 = __builtin_amdgcn_mfma_f32_16x16x32_f16(af[0][ks], wfb, d01, 0, 0, 0);
            d11 = __builtin_amdgcn_mfma_f32_16x16x32_f16(af[1][ks], wfb, d11, 0, 0, 0);
        }
        float bba = bias[cTa * 16 + n16], bbb = bias[cTb * 16 + n16];
#pragma unroll
        for (int rT = 0; rT < 2; ++rT) {
            const f32x4& da = rT ? d10 : d00;
            const f32x4& db = rT ? d11 : d01;
#pragma unroll
            for (int q2 = 0; q2 < 4; ++q2) {
                int row = rT * 16 + g * 4 + q2, swz = (row & 7) << 4;
                *(uint16_t*)(xpbuf + row * 256 + (((cTa * 16 + n16) * 2) ^ swz)) = f2h(fmaxf(da[q2] + bba, 0.0f));
                *(uint16_t*)(xpbuf + row * 256 + (((cTb * 16 + n16) * 2) ^ swz)) = f2h(fmaxf(db[q2] + bbb, 0.0f));
            }
        }
    }
    __syncthreads();

    // xf: this wave's 16 rows, held in registers for the whole loop (16 VGPR)
    f16x8 xf[4];
    {
        int row = rg * 16 + n16;
#pragma unroll
        for (int ks = 0; ks < 4; ++ks)
            xf[ks] = *(const f16x8*)(xpbuf + row * 256 + ((ks * 64 + g * 16) ^ swzP));
    }

    // ================= main loop (k-stride 2 per kh wave) ====================
    f32x4 zero4 = {0.f, 0.f, 0.f, 0.f};
    f32x4 acc[8];
#pragma unroll
    for (int c = 0; c < 8; ++c) acc[c] = zero4;
    float m_r = -INFINITY, l_r = 0.0f;
    float rww = rw[0];

    for (int kt = lo + kh; kt < hi; kt += 2) {
        const uint8_t* ybase = Y2 + ((size_t)kt << 14) + lane * 16;
        const uint8_t* vbase = V2 + ((size_t)kt << 14) + lane * 16;

        // ---- S^T: 16 MFMAs (rows rg*16..), y loads per-ks
        f32x4 ss[4];
#pragma unroll
        for (int kkT = 0; kkT < 4; ++kkT) ss[kkT] = zero4;
        __builtin_amdgcn_s_setprio(1);
#pragma unroll
        for (int ks = 0; ks < 4; ++ks) {
            f16x8 yf[4];
#pragma unroll
            for (int kkT = 0; kkT < 4; ++kkT)
                yf[kkT] = *(const f16x8*)(ybase + ((kkT * 4 + ks) << 10));
#pragma unroll
            for (int kkT = 0; kkT < 4; ++kkT)
                ss[kkT] = __builtin_amdgcn_mfma_f32_16x16x32_f16(yf[kkT], xf[ks], ss[kkT], 0, 0, 0);
        }
        __builtin_amdgcn_s_setprio(0);

        // ---- mask + recency bias
        float biasK = rww * (float)(t - kt);
#pragma unroll
        for (int kkT = 0; kkT < 4; ++kkT) {
            f32x4 ba = *(const f32x4*)(badd + kt * 64 + kkT * 16 + g * 4);
            ss[kkT] += (ba + biasK);
        }

        // ---- online row max (16 in-lane + cross-g shfl)
        f32x4 mx4 = ss[0];
#pragma unroll
        for (int kkT = 1; kkT < 4; ++kkT) {
            mx4[0] = fmaxf(mx4[0], ss[kkT][0]);
            mx4[1] = fmaxf(mx4[1], ss[kkT][1]);
            mx4[2] = fmaxf(mx4[2], ss[kkT][2]);
            mx4[3] = fmaxf(mx4[3], ss[kkT][3]);
        }
        float mx = fmaxf(fmaxf(mx4[0], mx4[1]), fmaxf(mx4[2], mx4[3]));
        mx = fmaxf(mx, __shfl_xor(mx, 16));
        mx = fmaxf(mx, __shfl_xor(mx, 32));
        float mn = fmaxf(m_r, mx);
        float sc = __expf(m_r - mn);
        m_r = mn;

        // ---- P = exp(s - m), running sum, P to wave-private LDS
        float ps = 0.0f;
#pragma unroll
        for (int kkT = 0; kkT < 4; ++kkT) {
            f32x4 p;
#pragma unroll
            for (int q2 = 0; q2 < 4; ++q2) p[q2] = __expf(ss[kkT][q2] - m_r);
            ps += (p[0] + p[1]) + (p[2] + p[3]);
            union { h16x2 h2[2]; uint64_t u64; } pk;
            pk.h2[0] = __builtin_amdgcn_cvt_pkrtz(p[0], p[1]);
            pk.h2[1] = __builtin_amdgcn_cvt_pkrtz(p[2], p[3]);
            *(uint64_t*)(Pw + n16 * 128 + ((kkT * 32 + g * 8) ^ swzP)) = pk.u64;
        }
        ps += __shfl_xor(ps, 16);
        ps += __shfl_xor(ps, 32);
        l_r = l_r * sc + ps;

        asm volatile("s_waitcnt lgkmcnt(0)" ::: "memory");

        // ---- rescale O (skip when max unchanged)
        if (!__all(sc == 1.0f)) {
            f32x4 s4;
#pragma unroll
            for (int q2 = 0; q2 < 4; ++q2) s4[q2] = __shfl(sc, (g << 2) + q2);
#pragma unroll
            for (int c = 0; c < 8; ++c) acc[c] *= s4;
        }

        // ---- PV: 16 MFMAs, v loads inline
        f16x8 pa0 = *(const f16x8*)(Pw + n16 * 128 + ((g * 16) ^ swzP));
        f16x8 pa1 = *(const f16x8*)(Pw + n16 * 128 + ((64 + g * 16) ^ swzP));
        __builtin_amdgcn_s_setprio(1);
#pragma unroll
        for (int cT = 0; cT < 8; ++cT) {
            f16x8 vb0 = *(const f16x8*)(vbase + ((cT * 2) << 10));
            f16x8 vb1 = *(const f16x8*)(vbase + ((cT * 2 + 1) << 10));
            acc[cT] = __builtin_amdgcn_mfma_f32_16x16x32_f16(pa0, vb0, acc[cT], 0, 0, 0);
            acc[cT] = __builtin_amdgcn_mfma_f32_16x16x32_f16(pa1, vb1, acc[cT], 0, 0, 0);
        }
        __builtin_amdgcn_s_setprio(0);
    }

    // ---- epilogue: combine kh pair per rg, write unnormalized partial
    if (g == 0) { stats_m[w][n16] = m_r; stats_l[w][n16] = l_r; }
    __syncthreads();

    float fac[4];
#pragma unroll
    for (int q2 = 0; q2 < 4; ++q2) {
        int rr = (g << 2) + q2;
        float m0 = stats_m[rg * 2][rr], m1 = stats_m[rg * 2 + 1][rr];
        float mf = fmaxf(m0, m1);
        float mw = stats_m[w][rr];
        fac[q2] = (mw == -INFINITY) ? 0.0f : __expf(mw - mf);
    }

    float* Ob = (float*)LDSA;      // 32 rows x 128 f32 = 16 KB (P/xpbuf dead)
    if (kh == 1) {
#pragma unroll
        for (int cT = 0; cT < 8; ++cT)
#pragma unroll
            for (int q2 = 0; q2 < 4; ++q2)
                Ob[(rg * 16 + (g << 2) + q2) * 128 + cT * 16 + n16] = acc[cT][q2] * fac[q2];
    }
    __syncthreads();
    if (kh == 0) {
        float* op = Opart + (size_t)bid * 4096;
#pragma unroll
        for (int cT = 0; cT < 8; ++cT)
#pragma unroll
            for (int q2 = 0; q2 < 4; ++q2) {
                int row = rg * 16 + (g << 2) + q2;
                op[(size_t)row * 128 + cT * 16 + n16] =
                    acc[cT][q2] * fac[q2] + Ob[row * 128 + cT * 16 + n16];
            }
    }

    if (tid < 32) {
        int rg2 = tid >> 4, rr = tid & 15;
        float m0 = stats_m[rg2 * 2][rr], m1 = stats_m[rg2 * 2 + 1][rr];
        float mf = fmaxf(m0, m1);
        float lf = stats_l[rg2 * 2][rr]     * ((m0 == -INFINITY) ? 0.0f : __expf(m0 - mf))
                 + stats_l[rg2 * 2 + 1][rr] * ((m1 == -INFINITY) ? 0.0f : __expf(m1 - mf));
        mstat[bid * 32 + tid] = mf;
        lstat[bid * 32 + tid] = lf;
    }
}

// ---------------------------------------------------------------------------
// Combine: one block per (t, l32). Folds the two k-half partials, normalizes.
// ---------------------------------------------------------------------------
__global__ __launch_bounds__(256) void combine_kernel(
        const float* __restrict__ Opart,
        const float* __restrict__ mstat,
        const float* __restrict__ lstat,
        float* __restrict__ out) {
    int c = blockIdx.x;
    int t = c >> 4, l = c & 15;
    int tid = threadIdx.x;
    float* obase = out + (size_t)(t * L1_ + l * 32) * H_;

    if (t == 0) {
        f32x4 z = {0.f, 0.f, 0.f, 0.f};
        f32x4* o4 = (f32x4*)obase;
        for (int i = tid; i < 32 * H_ / 4; i += 256) o4[i] = z;
        return;
    }

    int j0 = (t >= 16) ? (((31 - t) << 4) | l) : (256 + ((t << 4) | l));
    int j1 = j0 + 512;

    __shared__ float E0[32], E1[32], Li[32];
    if (tid < 32) {
        float m0 = mstat[j0 * 32 + tid], m1 = mstat[j1 * 32 + tid];
        float s0 = lstat[j0 * 32 + tid], s1 = lstat[j1 * 32 + tid];
        float M = fmaxf(m0, m1);
        float e0 = (m0 == -INFINITY) ? 0.0f : __expf(m0 - M);
        float e1 = (m1 == -INFINITY) ? 0.0f : __expf(m1 - M);
        float L = s0 * e0 + s1 * e1;
        E0[tid] = e0; E1[tid] = e1; Li[tid] = 1.0f / L;
    }
    __syncthreads();

    int rr = tid >> 3, cg = tid & 7;
    const f32x4* p0 = (const f32x4*)(Opart + (size_t)j0 * 4096 + rr * 128 + cg * 16);
    const f32x4* p1 = (const f32x4*)(Opart + (size_t)j1 * 4096 + rr * 128 + cg * 16);
    f32x4* po = (f32x4*)(obase + (size_t)rr * 128 + cg * 16);
    float e0 = E0[rr], e1 = E1[rr], li = Li[rr];
#pragma unroll
    for (int v = 0; v < 4; ++v)
        po[v] = (p0[v] * e0 + p1[v] * e1) * li;
}

// ---------------------------------------------------------------------------
extern "C" void kernel_launch(void* const* d_in, const int* in_sizes, int n_in,
                              void* d_out, int out_size, void* d_ws, size_t ws_size,
                              hipStream_t stream) {
    const float*   xd   = (const float*)d_in[0];
    const float*   xq   = (const float*)d_in[1];
    const float*   xa   = (const float*)d_in[2];
    const float*   W    = (const float*)d_in[3];
    const float*   bias = (const float*)d_in[4];
    const float*   rw   = (const float*)d_in[5];
    const uint8_t* qm   = (const uint8_t*)d_in[6];
    const uint8_t* am   = (const uint8_t*)d_in[7];
    float* out = (float*)d_out;

    char* ws = (char*)d_ws;
    float*   badd  = (float*)ws;                                  // 8 KB
    uint8_t* Y2    = (uint8_t*)(ws + 8192);                       // 512 KB
    uint8_t* V2    = (uint8_t*)(ws + 8192 + 524288);              // 512 KB
    uint8_t* W2    = (uint8_t*)(ws + 8192 + 2 * 524288);          // 32 KB
    float*   Opart = (float*)(ws + 2 * 1024 * 1024);              // 16 MB (1024 x 4096 f32)
    float*   mstat = (float*)(ws + 18 * 1024 * 1024);             // 128 KB
    float*   lstat = (float*)(ws + 18 * 1024 * 1024 + 131072);    // 128 KB

    preproc_kernel<<<162, 256, 0, stream>>>(xq, xa, W, bias, qm, am,
                                            Y2, V2, W2, badd);
    attn_kernel<<<1024, 256, 0, stream>>>(xd, W2, bias, Y2, V2, badd, rw,
                                          Opart, mstat, lstat);
    combine_kernel<<<512, 256, 0, stream>>>(Opart, mstat, lstat, out);
}

// Round 15
// 48.951 us; speedup vs baseline: 1.4367x; 1.4367x over previous
//
#include <hip/hip_runtime.h>
#include <stdint.h>
#include <math.h>

#define NEGV (-1e30f)

constexpr int L1_ = 512;
constexpr int H_  = 128;
constexpr int NK_ = 2048;   // 32 turns * 64 tokens

typedef __attribute__((ext_vector_type(8))) _Float16 f16x8;
typedef __attribute__((ext_vector_type(2))) __fp16   h16x2;
typedef __attribute__((ext_vector_type(4))) float    f32x4;

static __device__ __forceinline__ uint16_t f2h(float x) {
    union { _Float16 h; uint16_t u; } cv; cv.h = (_Float16)x; return cv.u;
}

// Fragment-major layouts (16B chunk per lane, lane = (g<<4)|n16):
//  Y2[kt(32)][kkT(4)][ks(4)][lane]  chunk = yp[kt*64+kkT*16+n16][ks*32+g*8 .. +8]
//  V2[kt(32)][cT(8)][ks(2)][lane]   chunk = dlg[kt*64+ks*32+g*8+j][cT*16+n16]
//  W2[cT(8)][ks(4)][lane]           chunk = W [cT*16+n16][ks*32+g*8 .. +8]

// ---------------------------------------------------------------------------
// Preprocessing, 256 threads/block (unchanged):
//  [0,128): yproj->Y2   [128,160): dlg->V2   160: badd   161: W->W2
// ---------------------------------------------------------------------------
__global__ __launch_bounds__(256) void preproc_kernel(
        const float* __restrict__ xq,
        const float* __restrict__ xa,
        const float* __restrict__ W,
        const float* __restrict__ bias,
        const uint8_t* __restrict__ qm,
        const uint8_t* __restrict__ am,
        uint8_t* __restrict__ Y2,
        uint8_t* __restrict__ V2,
        uint8_t* __restrict__ W2,
        float* __restrict__ badd) {
    int b = blockIdx.x;
    int tid = threadIdx.x;
    __shared__ __align__(16) float sbuf[64 * 128];   // 32 KB

    if (b < 128) {
        int k0 = b * 16;
        f32x4* xr4 = (f32x4*)sbuf;
#pragma unroll
        for (int i = 0; i < 2; ++i) {
            int idx = tid + i * 256;
            int row = idx >> 5, d4 = idx & 31;
            int k = k0 + row;
            int b2 = k >> 6, r = k & 63;
            const float* src = (r < 32) ? (xq + (size_t)(b2 * 32 + r) * H_)
                                        : (xa + (size_t)(b2 * 32 + (r - 32)) * H_);
            xr4[idx] = *(const f32x4*)(src + d4 * 4);
        }
        __syncthreads();
        int c = tid & 127, rh = tid >> 7;
        float acc[8];
#pragma unroll
        for (int i = 0; i < 8; ++i) acc[i] = 0.0f;
        const f32x4* w4 = (const f32x4*)(W + (size_t)c * H_);
        for (int d4 = 0; d4 < 32; ++d4) {
            f32x4 wv = w4[d4];
#pragma unroll
            for (int i = 0; i < 8; ++i) {
                f32x4 x = xr4[(rh * 8 + i) * 32 + d4];
                acc[i] += wv[0]*x[0] + wv[1]*x[1] + wv[2]*x[2] + wv[3]*x[3];
            }
        }
        float bc = bias[c];
        float* res = sbuf + 2048;
#pragma unroll
        for (int i = 0; i < 8; ++i)
            res[(rh * 8 + i) * H_ + c] = fmaxf(acc[i] + bc, 0.0f);
        __syncthreads();
        int ks = tid >> 6, l = tid & 63, n16 = l & 15, g = l >> 4;
        uint16_t hbuf[8];
#pragma unroll
        for (int j = 0; j < 8; ++j)
            hbuf[j] = f2h(res[n16 * H_ + ks * 32 + g * 8 + j]);
        uint8_t* dst = Y2 + (((size_t)b * 4 + ks) << 10) + l * 16;
        *(uint64_t*)dst       = ((const uint64_t*)hbuf)[0];
        *(uint64_t*)(dst + 8) = ((const uint64_t*)hbuf)[1];
    } else if (b < 160) {
        int kt = b - 128;
        f32x4* ld4 = (f32x4*)sbuf;
#pragma unroll
        for (int i = 0; i < 8; ++i) {
            int idx = tid + i * 256;
            int row = idx >> 5, d4 = idx & 31;
            const float* src = (row < 32) ? (xq + (size_t)(kt * 32 + row) * H_)
                                          : (xa + (size_t)(kt * 32 + row - 32) * H_);
            ld4[idx] = *(const f32x4*)(src + d4 * 4);
        }
        __syncthreads();
#pragma unroll
        for (int i = 0; i < 4; ++i) {
            int id = tid + i * 256;
            int cT = id >> 7, ks = (id >> 6) & 1, l = id & 63;
            int n16 = l & 15, g = l >> 4;
            uint16_t hbuf[8];
#pragma unroll
            for (int j = 0; j < 8; ++j)
                hbuf[j] = f2h(sbuf[(ks * 32 + g * 8 + j) * H_ + cT * 16 + n16]);
            uint8_t* dst = V2 + (((size_t)kt * 16 + cT * 2 + ks) << 10) + l * 16;
            *(uint64_t*)dst       = ((const uint64_t*)hbuf)[0];
            *(uint64_t*)(dst + 8) = ((const uint64_t*)hbuf)[1];
        }
    } else if (b == 160) {
        int* flags = (int*)sbuf;
        if (tid == 0) { flags[0] = 0; flags[1] = 0; }
        __syncthreads();
        uint32_t v = ((const uint32_t*)qm)[tid] | ((const uint32_t*)am)[tid];
        if (v & 0xFFu)        atomicOr(&flags[0], 1);
        if (v & 0xFFFFFF00u)  atomicOr(&flags[1], 1);
        __syncthreads();
        int f0 = flags[0], f1 = flags[1];
        int mode = (f0 && !f1) ? 0 : ((!f0 && f1) ? 1 : 2);
        for (int k = tid; k < NK_; k += 256) {
            int b2 = k >> 6, r = k & 63;
            int idx = b2 * 32 + (r < 32 ? r : r - 32);
            const uint8_t* src = (r < 32) ? qm : am;
            int p;
            if (mode == 0)      p = (((const int*)src)[idx] != 0);
            else if (mode == 1) p = (((const float*)src)[idx] != 0.0f);
            else                p = (src[idx] != 0);
            badd[k] = p ? NEGV : 0.0f;
        }
    } else {
        for (int h = 0; h < 2; ++h) {
            f32x4* s4 = (f32x4*)sbuf;
#pragma unroll
            for (int i = 0; i < 8; ++i) {
                int idx = tid + i * 256;
                s4[idx] = *(const f32x4*)(W + (size_t)h * 64 * H_ + idx * 4);
            }
            __syncthreads();
#pragma unroll
            for (int i = 0; i < 4; ++i) {
                int id = tid + i * 256;
                int ct = id >> 8, ks = (id >> 6) & 3, l = id & 63;
                int n16 = l & 15, g = l >> 4;
                uint16_t hb[8];
#pragma unroll
                for (int j = 0; j < 8; ++j)
                    hb[j] = f2h(sbuf[(ct * 16 + n16) * H_ + ks * 32 + g * 8 + j]);
                uint8_t* dst = W2 + (((size_t)((h * 4 + ct) * 4 + ks)) << 10) + l * 16;
                *(uint64_t*)dst       = ((const uint64_t*)hb)[0];
                *(uint64_t*)(dst + 8) = ((const uint64_t*)hb)[1];
            }
            __syncthreads();
        }
    }
}

// ---------------------------------------------------------------------------
// Flash attention, balanced split-K. Job = (t, l32, khalf). 256 thr / 4 waves,
// wave w: tiles kt = lo+w, step 4 (<=4 serial tiles). 128-VGPR budget
// ((256,2) — NOT (256,4) whose 64-VGPR cap forced a 125MB spill in R13).
// ---------------------------------------------------------------------------
__global__ __launch_bounds__(256, 2) void attn_kernel(
        const float*   __restrict__ xd,
        const uint8_t* __restrict__ W2,
        const float*   __restrict__ bias,
        const uint8_t* __restrict__ Y2,
        const uint8_t* __restrict__ V2,
        const float*   __restrict__ badd,
        const float*   __restrict__ rw,
        float* __restrict__ Opart,
        float* __restrict__ mstat,
        float* __restrict__ lstat) {
    int bid = blockIdx.x;
    int r8 = bid & 255, qq = bid >> 8;
    int tt = r8 >> 4, l = r8 & 15;
    int t = (qq & 1) ? tt : (31 - tt);
    int h = qq >> 1;
    if (t == 0) return;            // combine writes zeros for t=0
    int l0 = l << 5;
    int lo = h ? ((t + 1) >> 1) : 0;
    int hi = h ? t : ((t + 1) >> 1);
    int tid = threadIdx.x;

    __shared__ __align__(16) char LDSA[32768];  // P[0,16K) | xpbuf[16K,24K) | xbuf[24K,32K); epilogue Ob=[0,32K)
    __shared__ float stats_m[4][32];
    __shared__ float stats_l[4][32];

    int w = tid >> 6, lane = tid & 63, n16 = lane & 15, g = lane >> 4;
    int prow0 = n16, prow1 = 16 + n16;
    int swzP = (n16 & 7) << 4;
    char* xpbuf = LDSA + 16384;
    char* xbuf  = LDSA + 24576;
    char* Pw    = LDSA + w * 4096;

    // ================= x-projection prologue (MFMA) =================
    {
        const float* xsrc = xd + (size_t)(t * L1_ + l0) * H_;
#pragma unroll
        for (int i = 0; i < 4; ++i) {
            int idx = tid + i * 256;          // 1024 f32x4 = 32 rows
            int row = idx >> 5, c4 = idx & 31;
            f32x4 v = *(const f32x4*)(xsrc + idx * 4);
            uint16_t hb[4] = { f2h(v[0]), f2h(v[1]), f2h(v[2]), f2h(v[3]) };
            *(uint64_t*)(xbuf + row * 256 + ((c4 * 8) ^ ((row & 7) << 4))) = *(const uint64_t*)hb;
        }
    }
    __syncthreads();
    {
        f16x8 af[2][4];
#pragma unroll
        for (int rT = 0; rT < 2; ++rT) {
            int row = rT * 16 + n16, swz = (row & 7) << 4;
#pragma unroll
            for (int ks = 0; ks < 4; ++ks)
                af[rT][ks] = *(const f16x8*)(xbuf + row * 256 + ((ks * 64 + g * 16) ^ swz));
        }
        int cTa = 2 * w, cTb = 2 * w + 1;
        f32x4 z4 = {0.f, 0.f, 0.f, 0.f};
        f32x4 d00 = z4, d01 = z4, d10 = z4, d11 = z4;
#pragma unroll
        for (int ks = 0; ks < 4; ++ks) {
            f16x8 wfa = *(const f16x8*)(W2 + (((size_t)cTa * 4 + ks) << 10) + lane * 16);
            f16x8 wfb = *(const f16x8*)(W2 + (((size_t)cTb * 4 + ks) << 10) + lane * 16);
            d00 = __builtin_amdgcn_mfma_f32_16x16x32_f16(af[0][ks], wfa, d00, 0, 0, 0);
            d10 = __builtin_amdgcn_mfma_f32_16x16x32_f16(af[1][ks], wfa, d10, 0, 0, 0);
            d01 = __builtin_amdgcn_mfma_f32_16x16x32_f16(af[0][ks], wfb, d01, 0, 0, 0);
            d11 = __builtin_amdgcn_mfma_f32_16x16x32_f16(af[1][ks], wfb, d11, 0, 0, 0);
        }
        float bba = bias[cTa * 16 + n16], bbb = bias[cTb * 16 + n16];
#pragma unroll
        for (int rT = 0; rT < 2; ++rT) {
            const f32x4& da = rT ? d10 : d00;
            const f32x4& db = rT ? d11 : d01;
#pragma unroll
            for (int q2 = 0; q2 < 4; ++q2) {
                int row = rT * 16 + g * 4 + q2, swz = (row & 7) << 4;
                *(uint16_t*)(xpbuf + row * 256 + (((cTa * 16 + n16) * 2) ^ swz)) = f2h(fmaxf(da[q2] + bba, 0.0f));
                *(uint16_t*)(xpbuf + row * 256 + (((cTb * 16 + n16) * 2) ^ swz)) = f2h(fmaxf(db[q2] + bbb, 0.0f));
            }
        }
    }
    __syncthreads();

    // ================= main loop =================
    f32x4 zero4 = {0.f, 0.f, 0.f, 0.f};
    f32x4 acc[2][8];
#pragma unroll
    for (int a = 0; a < 2; ++a)
#pragma unroll
        for (int c = 0; c < 8; ++c) acc[a][c] = zero4;
    float m_r[2] = {-INFINITY, -INFINITY};
    float l_r[2] = {0.0f, 0.0f};
    float rww = rw[0];

    for (int kt = lo + w; kt < hi; kt += 4) {
        const uint8_t* ybase = Y2 + ((size_t)kt << 14) + lane * 16;
        const uint8_t* vbase = V2 + ((size_t)kt << 14) + lane * 16;

        // xf from LDS (loop-local to cap register pressure)
        f16x8 xf[2][4];
#pragma unroll
        for (int rT = 0; rT < 2; ++rT) {
            int row = rT * 16 + n16;
#pragma unroll
            for (int ks = 0; ks < 4; ++ks)
                xf[rT][ks] = *(const f16x8*)(xpbuf + row * 256 + ((ks * 64 + g * 16) ^ swzP));
        }

        // ---- S^T: 32 MFMAs, y loads per-ks (serialized; TLP hides)
        f32x4 ss[4][2];
#pragma unroll
        for (int kkT = 0; kkT < 4; ++kkT) { ss[kkT][0] = zero4; ss[kkT][1] = zero4; }
        __builtin_amdgcn_s_setprio(1);
#pragma unroll
        for (int ks = 0; ks < 4; ++ks) {
            f16x8 yf[4];
#pragma unroll
            for (int kkT = 0; kkT < 4; ++kkT)
                yf[kkT] = *(const f16x8*)(ybase + ((kkT * 4 + ks) << 10));
#pragma unroll
            for (int kkT = 0; kkT < 4; ++kkT) {
                ss[kkT][0] = __builtin_amdgcn_mfma_f32_16x16x32_f16(yf[kkT], xf[0][ks], ss[kkT][0], 0, 0, 0);
                ss[kkT][1] = __builtin_amdgcn_mfma_f32_16x16x32_f16(yf[kkT], xf[1][ks], ss[kkT][1], 0, 0, 0);
            }
        }
        __builtin_amdgcn_s_setprio(0);

        // ---- mask + recency bias
        float biasK = rww * (float)(t - kt);
#pragma unroll
        for (int kkT = 0; kkT < 4; ++kkT) {
            f32x4 ba = *(const f32x4*)(badd + kt * 64 + kkT * 16 + g * 4);
            ba += biasK;
            ss[kkT][0] += ba;
            ss[kkT][1] += ba;
        }

        // ---- per-row online max
        float sc[2];
#pragma unroll
        for (int rT = 0; rT < 2; ++rT) {
            f32x4 mx4 = ss[0][rT];
#pragma unroll
            for (int kkT = 1; kkT < 4; ++kkT) {
                mx4[0] = fmaxf(mx4[0], ss[kkT][rT][0]);
                mx4[1] = fmaxf(mx4[1], ss[kkT][rT][1]);
                mx4[2] = fmaxf(mx4[2], ss[kkT][rT][2]);
                mx4[3] = fmaxf(mx4[3], ss[kkT][rT][3]);
            }
            float mx = fmaxf(fmaxf(mx4[0], mx4[1]), fmaxf(mx4[2], mx4[3]));
            mx = fmaxf(mx, __shfl_xor(mx, 16));
            mx = fmaxf(mx, __shfl_xor(mx, 32));
            float mn = fmaxf(m_r[rT], mx);
            sc[rT] = __expf(m_r[rT] - mn);
            m_r[rT] = mn;
        }

        // ---- P = exp(s - m), partial sums, P to wave-private LDS
#pragma unroll
        for (int rT = 0; rT < 2; ++rT) {
            int rr = rT ? prow1 : prow0;
            float mn = m_r[rT];
            float ps = 0.0f;
#pragma unroll
            for (int kkT = 0; kkT < 4; ++kkT) {
                f32x4 p;
#pragma unroll
                for (int q2 = 0; q2 < 4; ++q2) p[q2] = __expf(ss[kkT][rT][q2] - mn);
                ps += (p[0] + p[1]) + (p[2] + p[3]);
                union { h16x2 h2[2]; uint64_t u64; } pk;
                pk.h2[0] = __builtin_amdgcn_cvt_pkrtz(p[0], p[1]);
                pk.h2[1] = __builtin_amdgcn_cvt_pkrtz(p[2], p[3]);
                *(uint64_t*)(Pw + rr * 128 + ((kkT * 32 + g * 8) ^ swzP)) = pk.u64;
            }
            ps += __shfl_xor(ps, 16);
            ps += __shfl_xor(ps, 32);
            l_r[rT] = l_r[rT] * sc[rT] + ps;
        }

        asm volatile("s_waitcnt lgkmcnt(0)" ::: "memory");

        // ---- rescale O (skip when max unchanged)
        if (!__all((sc[0] == 1.0f) && (sc[1] == 1.0f))) {
#pragma unroll
            for (int rT = 0; rT < 2; ++rT) {
                f32x4 s4;
#pragma unroll
                for (int q2 = 0; q2 < 4; ++q2) s4[q2] = __shfl(sc[rT], (g << 2) + q2);
#pragma unroll
                for (int cT = 0; cT < 8; ++cT) acc[rT][cT] *= s4;
            }
        }

        // ---- PV: 32 MFMAs, v loads inline
        f16x8 pa[2][2];
#pragma unroll
        for (int rT = 0; rT < 2; ++rT) {
            int rr = rT ? prow1 : prow0;
#pragma unroll
            for (int ks = 0; ks < 2; ++ks)
                pa[rT][ks] = *(const f16x8*)(Pw + rr * 128 + ((ks * 64 + g * 16) ^ swzP));
        }
        __builtin_amdgcn_s_setprio(1);
#pragma unroll
        for (int cT = 0; cT < 8; ++cT) {
            f16x8 vb0 = *(const f16x8*)(vbase + ((cT * 2) << 10));
            f16x8 vb1 = *(const f16x8*)(vbase + ((cT * 2 + 1) << 10));
#pragma unroll
            for (int rT = 0; rT < 2; ++rT) {
                acc[rT][cT] = __builtin_amdgcn_mfma_f32_16x16x32_f16(pa[rT][0], vb0, acc[rT][cT], 0, 0, 0);
                acc[rT][cT] = __builtin_amdgcn_mfma_f32_16x16x32_f16(pa[rT][1], vb1, acc[rT][cT], 0, 0, 0);
            }
        }
        __builtin_amdgcn_s_setprio(0);
    }

    // ---- epilogue: combine 4 waves into an unnormalized partial
    if (g == 0) {
        stats_m[w][n16]      = m_r[0];
        stats_m[w][16 + n16] = m_r[1];
        stats_l[w][n16]      = l_r[0];
        stats_l[w][16 + n16] = l_r[1];
    }
    __syncthreads();

    float fac[2][4];
#pragma unroll
    for (int rT = 0; rT < 2; ++rT)
#pragma unroll
        for (int q2 = 0; q2 < 4; ++q2) {
            int rr = rT * 16 + (g << 2) + q2;
            float mw = stats_m[w][rr];
            float mf = stats_m[0][rr];
#pragma unroll
            for (int wv = 1; wv < 4; ++wv) mf = fmaxf(mf, stats_m[wv][rr]);
            fac[rT][q2] = (mw == -INFINITY) ? 0.0f : __expf(mw - mf);
        }

    float* Ob = (float*)LDSA;      // 32 KB, P/xpbuf dead
    float* op = Opart + (size_t)bid * 4096;
    for (int rT = 0; rT < 2; ++rT) {
#pragma unroll
        for (int cT = 0; cT < 8; ++cT)
#pragma unroll
            for (int q2 = 0; q2 < 4; ++q2)
                Ob[w * 2048 + (cT * 4 + q2) * 64 + lane] = acc[rT][cT][q2] * fac[rT][q2];
        __syncthreads();
#pragma unroll
        for (int s = 0; s < 8; ++s) {
            int slot = w * 8 + s;
            float v = Ob[slot * 64 + lane] + Ob[2048 + slot * 64 + lane]
                    + Ob[4096 + slot * 64 + lane] + Ob[6144 + slot * 64 + lane];
            int cT = slot >> 2, q2 = slot & 3;
            op[(size_t)(rT * 16 + (g << 2) + q2) * 128 + cT * 16 + n16] = v;
        }
        __syncthreads();
    }

    if (tid < 32) {
        float mf = stats_m[0][tid];
#pragma unroll
        for (int wv = 1; wv < 4; ++wv) mf = fmaxf(mf, stats_m[wv][tid]);
        float lf = 0.0f;
#pragma unroll
        for (int wv = 0; wv < 4; ++wv) {
            float mw = stats_m[wv][tid];
            lf += stats_l[wv][tid] * ((mw == -INFINITY) ? 0.0f : __expf(mw - mf));
        }
        mstat[bid * 32 + tid] = mf;
        lstat[bid * 32 + tid] = lf;
    }
}

// ---------------------------------------------------------------------------
// Combine: one block per (t, l32). Folds the two k-half partials, normalizes.
// ---------------------------------------------------------------------------
__global__ __launch_bounds__(256) void combine_kernel(
        const float* __restrict__ Opart,
        const float* __restrict__ mstat,
        const float* __restrict__ lstat,
        float* __restrict__ out) {
    int c = blockIdx.x;
    int t = c >> 4, l = c & 15;
    int tid = threadIdx.x;
    float* obase = out + (size_t)(t * L1_ + l * 32) * H_;

    if (t == 0) {
        f32x4 z = {0.f, 0.f, 0.f, 0.f};
        f32x4* o4 = (f32x4*)obase;
        for (int i = tid; i < 32 * H_ / 4; i += 256) o4[i] = z;
        return;
    }

    int j0 = (t >= 16) ? (((31 - t) << 4) | l) : (256 + ((t << 4) | l));
    int j1 = j0 + 512;

    __shared__ float E0[32], E1[32], Li[32];
    if (tid < 32) {
        float m0 = mstat[j0 * 32 + tid], m1 = mstat[j1 * 32 + tid];
        float s0 = lstat[j0 * 32 + tid], s1 = lstat[j1 * 32 + tid];
        float M = fmaxf(m0, m1);
        float e0 = (m0 == -INFINITY) ? 0.0f : __expf(m0 - M);
        float e1 = (m1 == -INFINITY) ? 0.0f : __expf(m1 - M);
        float L = s0 * e0 + s1 * e1;
        E0[tid] = e0; E1[tid] = e1; Li[tid] = 1.0f / L;
    }
    __syncthreads();

    int rr = tid >> 3, cg = tid & 7;
    const f32x4* p0 = (const f32x4*)(Opart + (size_t)j0 * 4096 + rr * 128 + cg * 16);
    const f32x4* p1 = (const f32x4*)(Opart + (size_t)j1 * 4096 + rr * 128 + cg * 16);
    f32x4* po = (f32x4*)(obase + (size_t)rr * 128 + cg * 16);
    float e0 = E0[rr], e1 = E1[rr], li = Li[rr];
#pragma unroll
    for (int v = 0; v < 4; ++v)
        po[v] = (p0[v] * e0 + p1[v] * e1) * li;
}

// ---------------------------------------------------------------------------
extern "C" void kernel_launch(void* const* d_in, const int* in_sizes, int n_in,
                              void* d_out, int out_size, void* d_ws, size_t ws_size,
                              hipStream_t stream) {
    const float*   xd   = (const float*)d_in[0];
    const float*   xq   = (const float*)d_in[1];
    const float*   xa   = (const float*)d_in[2];
    const float*   W    = (const float*)d_in[3];
    const float*   bias = (const float*)d_in[4];
    const float*   rw   = (const float*)d_in[5];
    const uint8_t* qm   = (const uint8_t*)d_in[6];
    const uint8_t* am   = (const uint8_t*)d_in[7];
    float* out = (float*)d_out;

    char* ws = (char*)d_ws;
    float*   badd  = (float*)ws;                                  // 8 KB
    uint8_t* Y2    = (uint8_t*)(ws + 8192);                       // 512 KB
    uint8_t* V2    = (uint8_t*)(ws + 8192 + 524288);              // 512 KB
    uint8_t* W2    = (uint8_t*)(ws + 8192 + 2 * 524288);          // 32 KB
    float*   Opart = (float*)(ws + 2 * 1024 * 1024);              // 16 MB (1024 x 4096 f32)
    float*   mstat = (float*)(ws + 18 * 1024 * 1024);             // 128 KB
    float*   lstat = (float*)(ws + 18 * 1024 * 1024 + 131072);    // 128 KB

    preproc_kernel<<<162, 256, 0, stream>>>(xq, xa, W, bias, qm, am,
                                            Y2, V2, W2, badd);
    attn_kernel<<<1024, 256, 0, stream>>>(xd, W2, bias, Y2, V2, badd, rw,
                                          Opart, mstat, lstat);
    combine_kernel<<<512, 256, 0, stream>>>(Opart, mstat, lstat, out);
}

// Round 16
// 45.790 us; speedup vs baseline: 1.5359x; 1.0690x over previous
//
#include <hip/hip_runtime.h>
#include <stdint.h>
#include <math.h>

#define NEGV (-1e30f)

constexpr int L1_ = 512;
constexpr int H_  = 128;
constexpr int NK_ = 2048;   // 32 turns * 64 tokens

typedef __attribute__((ext_vector_type(8))) _Float16 f16x8;
typedef __attribute__((ext_vector_type(2))) __fp16   h16x2;
typedef __attribute__((ext_vector_type(4))) float    f32x4;

static __device__ __forceinline__ uint16_t f2h(float x) {
    union { _Float16 h; uint16_t u; } cv; cv.h = (_Float16)x; return cv.u;
}

// Fragment-major layouts (16B chunk per lane, lane = (g<<4)|n16):
//  Y2[kt(32)][kkT(4)][ks(4)][lane]  chunk = yp[kt*64+kkT*16+n16][ks*32+g*8 .. +8]
//  V2[kt(32)][cT(8)][ks(2)][lane]   chunk = dlg[kt*64+ks*32+g*8+j][cT*16+n16]
//  W2[cT(8)][ks(4)][lane]           chunk = W [cT*16+n16][ks*32+g*8 .. +8]

// Job map (work-equalized): bid = v*256 + a*32 + l*2 + h, a=0..7
//   v=0: t=31-a   v=1: t=16+a   v=2: t=15-a   v=3: t=a
// Under bid%256 -> CU, each CU's 4 blocks sum to exactly 31 k-tiles.

// ---------------------------------------------------------------------------
// Preprocessing, 256 threads/block (unchanged):
//  [0,128): yproj->Y2   [128,160): dlg->V2   160: badd   161: W->W2
// ---------------------------------------------------------------------------
__global__ __launch_bounds__(256) void preproc_kernel(
        const float* __restrict__ xq,
        const float* __restrict__ xa,
        const float* __restrict__ W,
        const float* __restrict__ bias,
        const uint8_t* __restrict__ qm,
        const uint8_t* __restrict__ am,
        uint8_t* __restrict__ Y2,
        uint8_t* __restrict__ V2,
        uint8_t* __restrict__ W2,
        float* __restrict__ badd) {
    int b = blockIdx.x;
    int tid = threadIdx.x;
    __shared__ __align__(16) float sbuf[64 * 128];   // 32 KB

    if (b < 128) {
        int k0 = b * 16;
        f32x4* xr4 = (f32x4*)sbuf;
#pragma unroll
        for (int i = 0; i < 2; ++i) {
            int idx = tid + i * 256;
            int row = idx >> 5, d4 = idx & 31;
            int k = k0 + row;
            int b2 = k >> 6, r = k & 63;
            const float* src = (r < 32) ? (xq + (size_t)(b2 * 32 + r) * H_)
                                        : (xa + (size_t)(b2 * 32 + (r - 32)) * H_);
            xr4[idx] = *(const f32x4*)(src + d4 * 4);
        }
        __syncthreads();
        int c = tid & 127, rh = tid >> 7;
        float acc[8];
#pragma unroll
        for (int i = 0; i < 8; ++i) acc[i] = 0.0f;
        const f32x4* w4 = (const f32x4*)(W + (size_t)c * H_);
        for (int d4 = 0; d4 < 32; ++d4) {
            f32x4 wv = w4[d4];
#pragma unroll
            for (int i = 0; i < 8; ++i) {
                f32x4 x = xr4[(rh * 8 + i) * 32 + d4];
                acc[i] += wv[0]*x[0] + wv[1]*x[1] + wv[2]*x[2] + wv[3]*x[3];
            }
        }
        float bc = bias[c];
        float* res = sbuf + 2048;
#pragma unroll
        for (int i = 0; i < 8; ++i)
            res[(rh * 8 + i) * H_ + c] = fmaxf(acc[i] + bc, 0.0f);
        __syncthreads();
        int ks = tid >> 6, l = tid & 63, n16 = l & 15, g = l >> 4;
        uint16_t hbuf[8];
#pragma unroll
        for (int j = 0; j < 8; ++j)
            hbuf[j] = f2h(res[n16 * H_ + ks * 32 + g * 8 + j]);
        uint8_t* dst = Y2 + (((size_t)b * 4 + ks) << 10) + l * 16;
        *(uint64_t*)dst       = ((const uint64_t*)hbuf)[0];
        *(uint64_t*)(dst + 8) = ((const uint64_t*)hbuf)[1];
    } else if (b < 160) {
        int kt = b - 128;
        f32x4* ld4 = (f32x4*)sbuf;
#pragma unroll
        for (int i = 0; i < 8; ++i) {
            int idx = tid + i * 256;
            int row = idx >> 5, d4 = idx & 31;
            const float* src = (row < 32) ? (xq + (size_t)(kt * 32 + row) * H_)
                                          : (xa + (size_t)(kt * 32 + row - 32) * H_);
            ld4[idx] = *(const f32x4*)(src + d4 * 4);
        }
        __syncthreads();
#pragma unroll
        for (int i = 0; i < 4; ++i) {
            int id = tid + i * 256;
            int cT = id >> 7, ks = (id >> 6) & 1, l = id & 63;
            int n16 = l & 15, g = l >> 4;
            uint16_t hbuf[8];
#pragma unroll
            for (int j = 0; j < 8; ++j)
                hbuf[j] = f2h(sbuf[(ks * 32 + g * 8 + j) * H_ + cT * 16 + n16]);
            uint8_t* dst = V2 + (((size_t)kt * 16 + cT * 2 + ks) << 10) + l * 16;
            *(uint64_t*)dst       = ((const uint64_t*)hbuf)[0];
            *(uint64_t*)(dst + 8) = ((const uint64_t*)hbuf)[1];
        }
    } else if (b == 160) {
        int* flags = (int*)sbuf;
        if (tid == 0) { flags[0] = 0; flags[1] = 0; }
        __syncthreads();
        uint32_t v = ((const uint32_t*)qm)[tid] | ((const uint32_t*)am)[tid];
        if (v & 0xFFu)        atomicOr(&flags[0], 1);
        if (v & 0xFFFFFF00u)  atomicOr(&flags[1], 1);
        __syncthreads();
        int f0 = flags[0], f1 = flags[1];
        int mode = (f0 && !f1) ? 0 : ((!f0 && f1) ? 1 : 2);
        for (int k = tid; k < NK_; k += 256) {
            int b2 = k >> 6, r = k & 63;
            int idx = b2 * 32 + (r < 32 ? r : r - 32);
            const uint8_t* src = (r < 32) ? qm : am;
            int p;
            if (mode == 0)      p = (((const int*)src)[idx] != 0);
            else if (mode == 1) p = (((const float*)src)[idx] != 0.0f);
            else                p = (src[idx] != 0);
            badd[k] = p ? NEGV : 0.0f;
        }
    } else {
        for (int h = 0; h < 2; ++h) {
            f32x4* s4 = (f32x4*)sbuf;
#pragma unroll
            for (int i = 0; i < 8; ++i) {
                int idx = tid + i * 256;
                s4[idx] = *(const f32x4*)(W + (size_t)h * 64 * H_ + idx * 4);
            }
            __syncthreads();
#pragma unroll
            for (int i = 0; i < 4; ++i) {
                int id = tid + i * 256;
                int ct = id >> 8, ks = (id >> 6) & 3, l = id & 63;
                int n16 = l & 15, g = l >> 4;
                uint16_t hb[8];
#pragma unroll
                for (int j = 0; j < 8; ++j)
                    hb[j] = f2h(sbuf[(ct * 16 + n16) * H_ + ks * 32 + g * 8 + j]);
                uint8_t* dst = W2 + (((size_t)((h * 4 + ct) * 4 + ks)) << 10) + l * 16;
                *(uint64_t*)dst       = ((const uint64_t*)hb)[0];
                *(uint64_t*)(dst + 8) = ((const uint64_t*)hb)[1];
            }
            __syncthreads();
        }
    }
}

// ---------------------------------------------------------------------------
// Flash attention, equalized split-K + fenced batch-issue (R8 body).
// Job = (t, l32, khalf); wave w: kt = lo+w, step 4 (<=4 serial tiles).
// ---------------------------------------------------------------------------
__global__ __launch_bounds__(256, 2) void attn_kernel(
        const float*   __restrict__ xd,
        const uint8_t* __restrict__ W2,
        const float*   __restrict__ bias,
        const uint8_t* __restrict__ Y2,
        const uint8_t* __restrict__ V2,
        const float*   __restrict__ badd,
        const float*   __restrict__ rw,
        float* __restrict__ Opart,
        float* __restrict__ mstat,
        float* __restrict__ lstat) {
    int bid = blockIdx.x;
    int v = bid >> 8, u = bid & 255;
    int a = u >> 5, r5 = u & 31;
    int t;
    if (v == 0)      t = 31 - a;
    else if (v == 1) t = 16 + a;
    else if (v == 2) t = 15 - a;
    else             t = a;
    int l = r5 >> 1, h = r5 & 1;
    if (t == 0) return;            // combine writes zeros for t=0
    int l0 = l << 5;
    int lo = h ? ((t + 1) >> 1) : 0;
    int hi = h ? t : ((t + 1) >> 1);
    int tid = threadIdx.x;

    __shared__ __align__(16) char LDSA[32768];  // P[0,16K) | xpbuf[16K,24K) | xbuf[24K,32K); epilogue Ob=[0,32K)
    __shared__ float stats_m[4][32];
    __shared__ float stats_l[4][32];

    int w = tid >> 6, lane = tid & 63, n16 = lane & 15, g = lane >> 4;
    int prow0 = n16, prow1 = 16 + n16;
    int swzP = (n16 & 7) << 4;
    char* xpbuf = LDSA + 16384;
    char* xbuf  = LDSA + 24576;
    char* Pw    = LDSA + w * 4096;

    // ================= x-projection prologue (MFMA) =================
    {
        const float* xsrc = xd + (size_t)(t * L1_ + l0) * H_;
#pragma unroll
        for (int i = 0; i < 4; ++i) {
            int idx = tid + i * 256;          // 1024 f32x4 = 32 rows
            int row = idx >> 5, c4 = idx & 31;
            f32x4 vv = *(const f32x4*)(xsrc + idx * 4);
            uint16_t hb[4] = { f2h(vv[0]), f2h(vv[1]), f2h(vv[2]), f2h(vv[3]) };
            *(uint64_t*)(xbuf + row * 256 + ((c4 * 8) ^ ((row & 7) << 4))) = *(const uint64_t*)hb;
        }
    }
    __syncthreads();
    {
        f16x8 af[2][4];
#pragma unroll
        for (int rT = 0; rT < 2; ++rT) {
            int row = rT * 16 + n16, swz = (row & 7) << 4;
#pragma unroll
            for (int ks = 0; ks < 4; ++ks)
                af[rT][ks] = *(const f16x8*)(xbuf + row * 256 + ((ks * 64 + g * 16) ^ swz));
        }
        int cTa = 2 * w, cTb = 2 * w + 1;
        f32x4 z4 = {0.f, 0.f, 0.f, 0.f};
        f32x4 d00 = z4, d01 = z4, d10 = z4, d11 = z4;
#pragma unroll
        for (int ks = 0; ks < 4; ++ks) {
            f16x8 wfa = *(const f16x8*)(W2 + (((size_t)cTa * 4 + ks) << 10) + lane * 16);
            f16x8 wfb = *(const f16x8*)(W2 + (((size_t)cTb * 4 + ks) << 10) + lane * 16);
            d00 = __builtin_amdgcn_mfma_f32_16x16x32_f16(af[0][ks], wfa, d00, 0, 0, 0);
            d10 = __builtin_amdgcn_mfma_f32_16x16x32_f16(af[1][ks], wfa, d10, 0, 0, 0);
            d01 = __builtin_amdgcn_mfma_f32_16x16x32_f16(af[0][ks], wfb, d01, 0, 0, 0);
            d11 = __builtin_amdgcn_mfma_f32_16x16x32_f16(af[1][ks], wfb, d11, 0, 0, 0);
        }
        float bba = bias[cTa * 16 + n16], bbb = bias[cTb * 16 + n16];
#pragma unroll
        for (int rT = 0; rT < 2; ++rT) {
            const f32x4& da = rT ? d10 : d00;
            const f32x4& db = rT ? d11 : d01;
#pragma unroll
            for (int q2 = 0; q2 < 4; ++q2) {
                int row = rT * 16 + g * 4 + q2, swz = (row & 7) << 4;
                *(uint16_t*)(xpbuf + row * 256 + (((cTa * 16 + n16) * 2) ^ swz)) = f2h(fmaxf(da[q2] + bba, 0.0f));
                *(uint16_t*)(xpbuf + row * 256 + (((cTb * 16 + n16) * 2) ^ swz)) = f2h(fmaxf(db[q2] + bbb, 0.0f));
            }
        }
    }
    __syncthreads();

    // xf held in registers for the whole loop (R8 pattern)
    f16x8 xf[2][4];
#pragma unroll
    for (int rT = 0; rT < 2; ++rT) {
        int row = rT * 16 + n16;
#pragma unroll
        for (int ks = 0; ks < 4; ++ks)
            xf[rT][ks] = *(const f16x8*)(xpbuf + row * 256 + ((ks * 64 + g * 16) ^ swzP));
    }

    // ================= main loop (fenced batch-issue per tile) ==============
    f32x4 zero4 = {0.f, 0.f, 0.f, 0.f};
    f32x4 acc[2][8];
#pragma unroll
    for (int aa = 0; aa < 2; ++aa)
#pragma unroll
        for (int c = 0; c < 8; ++c) acc[aa][c] = zero4;
    float m_r[2] = {-INFINITY, -INFINITY};
    float l_r[2] = {0.0f, 0.0f};
    float rww = rw[0];

    for (int kt = lo + w; kt < hi; kt += 4) {
        const uint8_t* ybase = Y2 + ((size_t)kt << 14) + lane * 16;
        const uint8_t* vbase = V2 + ((size_t)kt << 14) + lane * 16;

        // ---- batch-issue: 16 y + 8 vA + 4 badd loads, FENCE
        f16x8 yf[4][4];
#pragma unroll
        for (int kkT = 0; kkT < 4; ++kkT)
#pragma unroll
            for (int ks = 0; ks < 4; ++ks)
                yf[kkT][ks] = *(const f16x8*)(ybase + ((kkT * 4 + ks) << 10));
        f16x8 vbA[4][2];
#pragma unroll
        for (int cT = 0; cT < 4; ++cT) {
            vbA[cT][0] = *(const f16x8*)(vbase + ((cT * 2) << 10));
            vbA[cT][1] = *(const f16x8*)(vbase + ((cT * 2 + 1) << 10));
        }
        f32x4 ba4[4];
#pragma unroll
        for (int kkT = 0; kkT < 4; ++kkT)
            ba4[kkT] = *(const f32x4*)(badd + kt * 64 + kkT * 16 + g * 4);
        __builtin_amdgcn_sched_barrier(0);

        // ---- S^T: 32 MFMAs
        f32x4 ss[4][2];
#pragma unroll
        for (int kkT = 0; kkT < 4; ++kkT) { ss[kkT][0] = zero4; ss[kkT][1] = zero4; }
#pragma unroll
        for (int ks = 0; ks < 4; ++ks)
#pragma unroll
            for (int kkT = 0; kkT < 4; ++kkT) {
                ss[kkT][0] = __builtin_amdgcn_mfma_f32_16x16x32_f16(yf[kkT][ks], xf[0][ks], ss[kkT][0], 0, 0, 0);
                ss[kkT][1] = __builtin_amdgcn_mfma_f32_16x16x32_f16(yf[kkT][ks], xf[1][ks], ss[kkT][1], 0, 0, 0);
            }

        // ---- second-half v loads, FENCE (land under softmax)
        f16x8 vbB[4][2];
#pragma unroll
        for (int cT = 0; cT < 4; ++cT) {
            vbB[cT][0] = *(const f16x8*)(vbase + (((cT + 4) * 2) << 10));
            vbB[cT][1] = *(const f16x8*)(vbase + (((cT + 4) * 2 + 1) << 10));
        }
        __builtin_amdgcn_sched_barrier(0);

        // ---- mask + recency bias
        float biasK = rww * (float)(t - kt);
#pragma unroll
        for (int kkT = 0; kkT < 4; ++kkT) {
            f32x4 ba = ba4[kkT] + biasK;
            ss[kkT][0] += ba;
            ss[kkT][1] += ba;
        }

        // ---- per-row online max
        float sc[2];
#pragma unroll
        for (int rT = 0; rT < 2; ++rT) {
            f32x4 mx4 = ss[0][rT];
#pragma unroll
            for (int kkT = 1; kkT < 4; ++kkT) {
                mx4[0] = fmaxf(mx4[0], ss[kkT][rT][0]);
                mx4[1] = fmaxf(mx4[1], ss[kkT][rT][1]);
                mx4[2] = fmaxf(mx4[2], ss[kkT][rT][2]);
                mx4[3] = fmaxf(mx4[3], ss[kkT][rT][3]);
            }
            float mx = fmaxf(fmaxf(mx4[0], mx4[1]), fmaxf(mx4[2], mx4[3]));
            mx = fmaxf(mx, __shfl_xor(mx, 16));
            mx = fmaxf(mx, __shfl_xor(mx, 32));
            float mn = fmaxf(m_r[rT], mx);
            sc[rT] = __expf(m_r[rT] - mn);
            m_r[rT] = mn;
        }

        // ---- P = exp(s - m), partial sums, P to wave-private LDS
#pragma unroll
        for (int rT = 0; rT < 2; ++rT) {
            int rr = rT ? prow1 : prow0;
            float mn = m_r[rT];
            float ps = 0.0f;
#pragma unroll
            for (int kkT = 0; kkT < 4; ++kkT) {
                f32x4 p;
#pragma unroll
                for (int q2 = 0; q2 < 4; ++q2) p[q2] = __expf(ss[kkT][rT][q2] - mn);
                ps += (p[0] + p[1]) + (p[2] + p[3]);
                union { h16x2 h2[2]; uint64_t u64; } pk;
                pk.h2[0] = __builtin_amdgcn_cvt_pkrtz(p[0], p[1]);
                pk.h2[1] = __builtin_amdgcn_cvt_pkrtz(p[2], p[3]);
                *(uint64_t*)(Pw + rr * 128 + ((kkT * 32 + g * 8) ^ swzP)) = pk.u64;
            }
            ps += __shfl_xor(ps, 16);
            ps += __shfl_xor(ps, 32);
            l_r[rT] = l_r[rT] * sc[rT] + ps;
        }

        asm volatile("s_waitcnt lgkmcnt(0)" ::: "memory");

        // ---- rescale O (skip when max unchanged)
        if (!__all((sc[0] == 1.0f) && (sc[1] == 1.0f))) {
#pragma unroll
            for (int rT = 0; rT < 2; ++rT) {
                f32x4 s4;
#pragma unroll
                for (int q2 = 0; q2 < 4; ++q2) s4[q2] = __shfl(sc[rT], (g << 2) + q2);
#pragma unroll
                for (int cT = 0; cT < 8; ++cT) acc[rT][cT] *= s4;
            }
        }

        // ---- PV: 32 MFMAs, v regs long since landed
        f16x8 pa[2][2];
#pragma unroll
        for (int rT = 0; rT < 2; ++rT) {
            int rr = rT ? prow1 : prow0;
#pragma unroll
            for (int ks = 0; ks < 2; ++ks)
                pa[rT][ks] = *(const f16x8*)(Pw + rr * 128 + ((ks * 64 + g * 16) ^ swzP));
        }
#pragma unroll
        for (int cT = 0; cT < 4; ++cT)
#pragma unroll
            for (int rT = 0; rT < 2; ++rT) {
                acc[rT][cT] = __builtin_amdgcn_mfma_f32_16x16x32_f16(pa[rT][0], vbA[cT][0], acc[rT][cT], 0, 0, 0);
                acc[rT][cT] = __builtin_amdgcn_mfma_f32_16x16x32_f16(pa[rT][1], vbA[cT][1], acc[rT][cT], 0, 0, 0);
            }
#pragma unroll
        for (int cT = 0; cT < 4; ++cT)
#pragma unroll
            for (int rT = 0; rT < 2; ++rT) {
                acc[rT][cT + 4] = __builtin_amdgcn_mfma_f32_16x16x32_f16(pa[rT][0], vbB[cT][0], acc[rT][cT + 4], 0, 0, 0);
                acc[rT][cT + 4] = __builtin_amdgcn_mfma_f32_16x16x32_f16(pa[rT][1], vbB[cT][1], acc[rT][cT + 4], 0, 0, 0);
            }
    }

    // ---- epilogue: combine 4 waves into an unnormalized partial
    if (g == 0) {
        stats_m[w][n16]      = m_r[0];
        stats_m[w][16 + n16] = m_r[1];
        stats_l[w][n16]      = l_r[0];
        stats_l[w][16 + n16] = l_r[1];
    }
    __syncthreads();

    float fac[2][4];
#pragma unroll
    for (int rT = 0; rT < 2; ++rT)
#pragma unroll
        for (int q2 = 0; q2 < 4; ++q2) {
            int rr = rT * 16 + (g << 2) + q2;
            float mw = stats_m[w][rr];
            float mf = stats_m[0][rr];
#pragma unroll
            for (int wv = 1; wv < 4; ++wv) mf = fmaxf(mf, stats_m[wv][rr]);
            fac[rT][q2] = (mw == -INFINITY) ? 0.0f : __expf(mw - mf);
        }

    float* Ob = (float*)LDSA;      // 32 KB, P/xpbuf dead
    float* op = Opart + (size_t)bid * 4096;
    for (int rT = 0; rT < 2; ++rT) {
#pragma unroll
        for (int cT = 0; cT < 8; ++cT)
#pragma unroll
            for (int q2 = 0; q2 < 4; ++q2)
                Ob[w * 2048 + (cT * 4 + q2) * 64 + lane] = acc[rT][cT][q2] * fac[rT][q2];
        __syncthreads();
#pragma unroll
        for (int s = 0; s < 8; ++s) {
            int slot = w * 8 + s;
            float vv = Ob[slot * 64 + lane] + Ob[2048 + slot * 64 + lane]
                     + Ob[4096 + slot * 64 + lane] + Ob[6144 + slot * 64 + lane];
            int cT = slot >> 2, q2 = slot & 3;
            op[(size_t)(rT * 16 + (g << 2) + q2) * 128 + cT * 16 + n16] = vv;
        }
        __syncthreads();
    }

    if (tid < 32) {
        float mf = stats_m[0][tid];
#pragma unroll
        for (int wv = 1; wv < 4; ++wv) mf = fmaxf(mf, stats_m[wv][tid]);
        float lf = 0.0f;
#pragma unroll
        for (int wv = 0; wv < 4; ++wv) {
            float mw = stats_m[wv][tid];
            lf += stats_l[wv][tid] * ((mw == -INFINITY) ? 0.0f : __expf(mw - mf));
        }
        mstat[bid * 32 + tid] = mf;
        lstat[bid * 32 + tid] = lf;
    }
}

// ---------------------------------------------------------------------------
// Combine: one block per (t, l32). Folds the two k-half partials, normalizes.
// ---------------------------------------------------------------------------
__global__ __launch_bounds__(256) void combine_kernel(
        const float* __restrict__ Opart,
        const float* __restrict__ mstat,
        const float* __restrict__ lstat,
        float* __restrict__ out) {
    int c = blockIdx.x;
    int t = c >> 4, l = c & 15;
    int tid = threadIdx.x;
    float* obase = out + (size_t)(t * L1_ + l * 32) * H_;

    if (t == 0) {
        f32x4 z = {0.f, 0.f, 0.f, 0.f};
        f32x4* o4 = (f32x4*)obase;
        for (int i = tid; i < 32 * H_ / 4; i += 256) o4[i] = z;
        return;
    }

    // invert the job map: (t) -> (v,a)
    int v, a;
    if (t >= 24)      { v = 0; a = 31 - t; }
    else if (t >= 16) { v = 1; a = t - 16; }
    else if (t >= 8)  { v = 2; a = 15 - t; }
    else              { v = 3; a = t; }
    int j0 = v * 256 + a * 32 + l * 2;
    int j1 = j0 + 1;

    __shared__ float E0[32], E1[32], Li[32];
    if (tid < 32) {
        float m0 = mstat[j0 * 32 + tid], m1 = mstat[j1 * 32 + tid];
        float s0 = lstat[j0 * 32 + tid], s1 = lstat[j1 * 32 + tid];
        float M = fmaxf(m0, m1);
        float e0 = (m0 == -INFINITY) ? 0.0f : __expf(m0 - M);
        float e1 = (m1 == -INFINITY) ? 0.0f : __expf(m1 - M);
        float L = s0 * e0 + s1 * e1;
        E0[tid] = e0; E1[tid] = e1; Li[tid] = 1.0f / L;
    }
    __syncthreads();

    int rr = tid >> 3, cg = tid & 7;
    const f32x4* p0 = (const f32x4*)(Opart + (size_t)j0 * 4096 + rr * 128 + cg * 16);
    const f32x4* p1 = (const f32x4*)(Opart + (size_t)j1 * 4096 + rr * 128 + cg * 16);
    f32x4* po = (f32x4*)(obase + (size_t)rr * 128 + cg * 16);
    float e0 = E0[rr], e1 = E1[rr], li = Li[rr];
#pragma unroll
    for (int vv = 0; vv < 4; ++vv)
        po[vv] = (p0[vv] * e0 + p1[vv] * e1) * li;
}

// ---------------------------------------------------------------------------
extern "C" void kernel_launch(void* const* d_in, const int* in_sizes, int n_in,
                              void* d_out, int out_size, void* d_ws, size_t ws_size,
                              hipStream_t stream) {
    const float*   xd   = (const float*)d_in[0];
    const float*   xq   = (const float*)d_in[1];
    const float*   xa   = (const float*)d_in[2];
    const float*   W    = (const float*)d_in[3];
    const float*   bias = (const float*)d_in[4];
    const float*   rw   = (const float*)d_in[5];
    const uint8_t* qm   = (const uint8_t*)d_in[6];
    const uint8_t* am   = (const uint8_t*)d_in[7];
    float* out = (float*)d_out;

    char* ws = (char*)d_ws;
    float*   badd  = (float*)ws;                                  // 8 KB
    uint8_t* Y2    = (uint8_t*)(ws + 8192);                       // 512 KB
    uint8_t* V2    = (uint8_t*)(ws + 8192 + 524288);              // 512 KB
    uint8_t* W2    = (uint8_t*)(ws + 8192 + 2 * 524288);          // 32 KB
    float*   Opart = (float*)(ws + 2 * 1024 * 1024);              // 16 MB (1024 x 4096 f32)
    float*   mstat = (float*)(ws + 18 * 1024 * 1024);             // 128 KB
    float*   lstat = (float*)(ws + 18 * 1024 * 1024 + 131072);    // 128 KB

    preproc_kernel<<<162, 256, 0, stream>>>(xq, xa, W, bias, qm, am,
                                            Y2, V2, W2, badd);
    attn_kernel<<<1024, 256, 0, stream>>>(xd, W2, bias, Y2, V2, badd, rw,
                                          Opart, mstat, lstat);
    combine_kernel<<<512, 256, 0, stream>>>(Opart, mstat, lstat, out);
}